// Round 1
// baseline (2364.328 us; speedup 1.0000x reference)
//
#include <hip/hip_runtime.h>
#include <hip/hip_bf16.h>
#include <math.h>

#define BATCH 32
#define TSEQ  64
#define KATTR 5
#define VOCAB 32000
#define DE    300
#define DA    300
#define DI    2048
#define HDIM  512
#define G4    2048            // 4*H
#define FEATK (DI + DA)       // 2348

// ---------------------------------------------------------------- utility
__global__ void zero_kernel(float* __restrict__ p, int n) {
    int i = blockIdx.x * blockDim.x + threadIdx.x;
    if (i < n) p[i] = 0.f;
}

// ---------------------------------------------------------------- K1: mean attr embedding
__global__ void mean_attr_kernel(const int* __restrict__ topk,
                                 const float* __restrict__ attr_emb,
                                 float* __restrict__ mean_attr) {
    int b = blockIdx.x;
    int tid = threadIdx.x;
    if (tid < DA) {
        float s = 0.f;
        #pragma unroll
        for (int q = 0; q < KATTR; ++q) {
            int a = topk[b * KATTR + q];
            s += attr_emb[(size_t)a * DA + tid];
        }
        mean_attr[b * DA + tid] = s / (float)KATTR;
    }
}

// ---------------------------------------------------------------- K2a: zf[b][j] = bias + img@Wimg + mean_attr@Wattr
__launch_bounds__(256)
__global__ void zf_kernel(const float* __restrict__ img,
                          const float* __restrict__ mean_attr,
                          const float* __restrict__ Wk,
                          const float* __restrict__ bias,
                          float* __restrict__ zf) {
    int b = blockIdx.y;
    int j = blockIdx.x * 256 + threadIdx.x;
    float acc = bias[j];
    const float* wimg = Wk + (size_t)DE * G4 + j;
    const float* irow = img + b * DI;
    #pragma unroll 8
    for (int k = 0; k < DI; ++k) acc += irow[k] * wimg[(size_t)k * G4];
    const float* wattr = Wk + (size_t)(DE + DI) * G4 + j;
    const float* arow = mean_attr + b * DA;
    #pragma unroll 4
    for (int k = 0; k < DA; ++k) acc += arow[k] * wattr[(size_t)k * G4];
    zf[b * G4 + j] = acc;
}

// ---------------------------------------------------------------- tiled fp32 GEMM, 64x64x16, 256 thr, 4x4/thread
// C[m][n] = sum_k A[m][k]*B[k][n] + add   (A optionally row-gathered)
// PERROW: add = addv[(m>>6)*N + n]  (zf broadcast over t, T=64)
// else:   add = addv[n]             (bias)
template<bool GATHER, bool PERROW>
__launch_bounds__(256)
__global__ void gemm_tile(const float* __restrict__ A,
                          const int* __restrict__ gidx,
                          const float* __restrict__ Bm,
                          const float* __restrict__ addv,
                          float* __restrict__ C,
                          int M, int N, int K, int lda) {
    __shared__ __align__(16) float As[16][68];   // [k][m]
    __shared__ __align__(16) float Bs[16][68];   // [k][n]
    const int tid = threadIdx.x;
    const int n0 = blockIdx.x * 64;
    const int m0 = blockIdx.y * 64;
    const int tx = tid & 15, ty = tid >> 4;
    const int ar  = tid >> 2;          // 0..63 A row in tile
    const int akq = (tid & 3) << 2;    // k quad
    const int bkr = tid >> 4;          // 0..15 B k row
    const int bc  = (tid & 15) << 2;   // B col quad

    size_t arow;
    if (GATHER) arow = (size_t)gidx[m0 + ar] * (size_t)lda;
    else        arow = (size_t)(m0 + ar) * (size_t)lda;

    float a00=0,a01=0,a02=0,a03=0, a10=0,a11=0,a12=0,a13=0;
    float a20=0,a21=0,a22=0,a23=0, a30=0,a31=0,a32=0,a33=0;

    for (int k0 = 0; k0 < K; k0 += 16) {
        int ka = k0 + akq;
        float4 av;
        if (ka + 4 <= K) {
            av = *(const float4*)(A + arow + ka);
        } else {
            av.x = (ka + 0 < K) ? A[arow + ka + 0] : 0.f;
            av.y = (ka + 1 < K) ? A[arow + ka + 1] : 0.f;
            av.z = (ka + 2 < K) ? A[arow + ka + 2] : 0.f;
            av.w = (ka + 3 < K) ? A[arow + ka + 3] : 0.f;
        }
        As[akq + 0][ar] = av.x;
        As[akq + 1][ar] = av.y;
        As[akq + 2][ar] = av.z;
        As[akq + 3][ar] = av.w;

        int kb = k0 + bkr;
        float4 bv;
        if (kb < K) bv = *(const float4*)(Bm + (size_t)kb * N + n0 + bc);
        else { bv.x = bv.y = bv.z = bv.w = 0.f; }
        *(float4*)&Bs[bkr][bc] = bv;

        __syncthreads();
        #pragma unroll
        for (int kk = 0; kk < 16; ++kk) {
            const float4 a4 = *(const float4*)&As[kk][ty << 2];
            const float4 b4 = *(const float4*)&Bs[kk][tx << 2];
            a00 += a4.x * b4.x; a01 += a4.x * b4.y; a02 += a4.x * b4.z; a03 += a4.x * b4.w;
            a10 += a4.y * b4.x; a11 += a4.y * b4.y; a12 += a4.y * b4.z; a13 += a4.y * b4.w;
            a20 += a4.z * b4.x; a21 += a4.z * b4.y; a22 += a4.z * b4.z; a23 += a4.z * b4.w;
            a30 += a4.w * b4.x; a31 += a4.w * b4.y; a32 += a4.w * b4.z; a33 += a4.w * b4.w;
        }
        __syncthreads();
    }

    float accs[4][4] = {{a00,a01,a02,a03},{a10,a11,a12,a13},{a20,a21,a22,a23},{a30,a31,a32,a33}};
    const int n = n0 + (tx << 2);
    #pragma unroll
    for (int i = 0; i < 4; ++i) {
        int m = m0 + (ty << 2) + i;
        const float* av2 = PERROW ? (addv + (size_t)(m >> 6) * N) : addv;
        float4 o;
        o.x = accs[i][0] + av2[n + 0];
        o.y = accs[i][1] + av2[n + 1];
        o.z = accs[i][2] + av2[n + 2];
        o.w = accs[i][3] + av2[n + 3];
        *(float4*)(C + (size_t)m * N + n) = o;
    }
}

// ---------------------------------------------------------------- K3: one LSTM step
// grid (8 kt, 32 b), 256 thr. thread -> gate = tid>>6, kk = tid&63, j = gate*512 + kt*64 + kk
__launch_bounds__(256)
__global__ void lstm_step(const float* __restrict__ z_pre,
                          const float* __restrict__ Wk,
                          const float* __restrict__ h_in,
                          float* __restrict__ h_out,
                          float* __restrict__ cbuf,
                          float* __restrict__ h_seq,
                          const int* __restrict__ lengths,
                          int t) {
    __shared__ float hs[HDIM];
    __shared__ float zbuf[256];
    const int b = blockIdx.y, kt = blockIdx.x, tid = threadIdx.x;
    hs[tid]       = h_in[b * HDIM + tid];
    hs[tid + 256] = h_in[b * HDIM + tid + 256];
    __syncthreads();

    const int gate = tid >> 6, kk = tid & 63;
    const int j = gate * HDIM + kt * 64 + kk;
    float acc = z_pre[((size_t)(b * TSEQ + t)) * G4 + j];
    const float* wcol = Wk + (size_t)(DE + DI + DA) * G4 + j;
    #pragma unroll 8
    for (int k = 0; k < HDIM; ++k) acc += hs[k] * wcol[(size_t)k * G4];
    zbuf[tid] = acc;
    __syncthreads();

    if (tid < 64) {
        float zi = zbuf[tid];
        float zF = zbuf[64 + tid];
        float zg = zbuf[128 + tid];
        float zo = zbuf[192 + tid];
        int kg = kt * 64 + tid;
        int ci = b * HDIM + kg;
        float c_old = cbuf[ci];
        float si = 1.f / (1.f + expf(-zi));
        float sf = 1.f / (1.f + expf(-zF));
        float so = 1.f / (1.f + expf(-zo));
        float c_new = sf * c_old + si * tanhf(zg);
        float h_new = so * tanhf(c_new);
        cbuf[ci] = c_new;
        h_out[ci] = h_new;
        h_seq[((size_t)(b * TSEQ + t)) * HDIM + kg] = (t < lengths[b]) ? h_new : 0.f;
    }
}

// ---------------------------------------------------------------- K5: argmax per row (first-occurrence)
__launch_bounds__(256)
__global__ void argmax_kernel(const float* __restrict__ logits, float* __restrict__ outa) {
    const int row = blockIdx.x;
    const int tid = threadIdx.x;
    const float* p = logits + (size_t)row * VOCAB;
    float bv = -INFINITY; int bi = VOCAB;
    for (int v = tid; v < VOCAB; v += 256) {
        float x = p[v];
        if (x > bv) { bv = x; bi = v; }   // strict > keeps first occurrence within thread
    }
    __shared__ float sv[256];
    __shared__ int   si[256];
    sv[tid] = bv; si[tid] = bi;
    __syncthreads();
    for (int s = 128; s > 0; s >>= 1) {
        if (tid < s) {
            if (sv[tid + s] > sv[tid] || (sv[tid + s] == sv[tid] && si[tid + s] < si[tid])) {
                sv[tid] = sv[tid + s]; si[tid] = si[tid + s];
            }
        }
        __syncthreads();
    }
    if (tid == 0) outa[row] = (float)si[0];
}

// ---------------------------------------------------------------- launcher
extern "C" void kernel_launch(void* const* d_in, const int* in_sizes, int n_in,
                              void* d_out, int out_size, void* d_ws, size_t ws_size,
                              hipStream_t stream) {
    const int*   topk     = (const int*)d_in[0];
    const float* img      = (const float*)d_in[1];
    const int*   seq      = (const int*)d_in[2];
    const int*   lengths  = (const int*)d_in[3];
    const float* word_emb = (const float*)d_in[4];
    const float* attr_emb = (const float*)d_in[5];
    const float* Wk       = (const float*)d_in[6];
    const float* bias     = (const float*)d_in[7];
    const float* Wlog     = (const float*)d_in[8];
    const float* blog     = (const float*)d_in[9];

    float* out_logits = (float*)d_out;
    float* out_argmax = out_logits + (size_t)BATCH * TSEQ * VOCAB;

    // ws layout (floats): mean_attr | zf | c | h0 | h1 | h_seq   (~4.7 MB)
    float* ws        = (float*)d_ws;
    float* mean_attr = ws;
    float* zf        = mean_attr + BATCH * DA;
    float* cbuf      = zf + BATCH * G4;
    float* hb0       = cbuf + BATCH * HDIM;
    float* hb1       = hb0 + BATCH * HDIM;
    float* h_seq     = hb1 + BATCH * HDIM;
    // z_pre (16.8 MB) staged inside d_out's logits region; fully consumed by the
    // LSTM scan before the logits GEMM overwrites it.
    float* z_pre     = out_logits;

    // zero c and h0 (adjacent, 2*B*H floats)
    zero_kernel<<<dim3((2 * BATCH * HDIM + 255) / 256), 256, 0, stream>>>(cbuf, 2 * BATCH * HDIM);

    mean_attr_kernel<<<dim3(BATCH), 320, 0, stream>>>(topk, attr_emb, mean_attr);

    zf_kernel<<<dim3(G4 / 256, BATCH), 256, 0, stream>>>(img, mean_attr, Wk, bias, zf);

    // z_pre[b*T+t][j] = word_emb[seq]@Wx + zf[b][j]
    gemm_tile<true, true><<<dim3(G4 / 64, (BATCH * TSEQ) / 64), 256, 0, stream>>>(
        word_emb, seq, Wk, zf, z_pre, BATCH * TSEQ, G4, DE, DE);

    // sequential scan
    float* hin = hb0;
    float* hout = hb1;
    for (int t = 0; t < TSEQ; ++t) {
        lstm_step<<<dim3(8, BATCH), 256, 0, stream>>>(z_pre, Wk, hin, hout, cbuf, h_seq, lengths, t);
        float* tmp = hin; hin = hout; hout = tmp;
    }

    // logits = h_seq @ W_logits + b_logits
    gemm_tile<false, false><<<dim3(VOCAB / 64, (BATCH * TSEQ) / 64), 256, 0, stream>>>(
        h_seq, nullptr, Wlog, blog, out_logits, BATCH * TSEQ, VOCAB, HDIM, HDIM);

    argmax_kernel<<<dim3(BATCH * TSEQ), 256, 0, stream>>>(out_logits, out_argmax);
}